// Round 13
// baseline (119.667 us; speedup 1.0000x reference)
//
#include <hip/hip_runtime.h>
#include <cstdint>
#include <cstddef>

// ---------------- types ----------------
typedef __bf16 bf16x8 __attribute__((ext_vector_type(8)));
typedef __bf16 bf16x4 __attribute__((ext_vector_type(4)));
typedef float  f32x4  __attribute__((ext_vector_type(4)));
typedef short  s16x4  __attribute__((ext_vector_type(4)));

#define DIMD 1024
#define SEQ  2048
#define NB   2
#define NH   16
#define HD   64
#define QKVN 1536   // 1024 + 2*256
#define VOFF 1280   // DIMD + 256
#define VSTR 2080   // padded V^T row stride (4160B: breaks L2 channel aliasing)
#define CSC  0.18033688011112042f   // 0.125 * log2(e), folded into q in GEMM1

// async global->LDS (16B per lane, wave-uniform LDS base)
typedef __attribute__((address_space(1))) const void* as1_cvp;
typedef __attribute__((address_space(3))) void* as3_vp;
#define GLL16(g, l) __builtin_amdgcn_global_load_lds((as1_cvp)(const void*)(g), (as3_vp)(void*)(l), 16, 0, 0)

// ---------------- fp32 -> bf16 elementwise (vec4) ----------------
__global__ void cvt_f32_bf16(const float* __restrict__ in, __bf16* __restrict__ out, int n4) {
    int i = blockIdx.x * blockDim.x + threadIdx.x;
    if (i >= n4) return;
    float4 v = reinterpret_cast<const float4*>(in)[i];
    bf16x4 o;
    o[0] = (__bf16)v.x; o[1] = (__bf16)v.y; o[2] = (__bf16)v.z; o[3] = (__bf16)v.w;
    reinterpret_cast<bf16x4*>(out)[i] = o;
}

// ---------------- fp32 [R][C] -> bf16 [C][R] tiled transpose ----------------
__global__ void transpose_cvt(const float* __restrict__ in, __bf16* __restrict__ out, int R, int C) {
    __shared__ float t[32][33];
    int bx = blockIdx.x * 32;
    int by = blockIdx.y * 32;
    int tx = threadIdx.x, ty = threadIdx.y;   // (32, 8)
#pragma unroll
    for (int i = 0; i < 32; i += 8)
        t[ty + i][tx] = in[(size_t)(by + ty + i) * C + bx + tx];
    __syncthreads();
#pragma unroll
    for (int i = 0; i < 32; i += 8)
        out[(size_t)(bx + ty + i) * R + by + tx] = (__bf16)t[tx][ty + i];
}

// ---------------- bf16 [S][64] V-slice of qkv -> bf16 Vt[z][64][VSTR] ----------------
__global__ void transpose_v(const __bf16* __restrict__ qkv, __bf16* __restrict__ vtg) {
    __shared__ __bf16 t[32][34];
    const int z = blockIdx.z;           // b*4 + kh
    const int b = z >> 2, kh = z & 3;
    const int s0 = blockIdx.x * 32, d0 = blockIdx.y * 32;
    const int tx = threadIdx.x, ty = threadIdx.y;   // (32, 8)
    const __bf16* src = qkv + (size_t)b * SEQ * QKVN + VOFF + kh * HD;
#pragma unroll
    for (int i = 0; i < 32; i += 8)
        t[ty + i][tx] = src[(size_t)(s0 + ty + i) * QKVN + d0 + tx];
    __syncthreads();
    __bf16* dst = vtg + ((size_t)z * HD + d0) * VSTR + s0;
#pragma unroll
    for (int i = 0; i < 32; i += 8)
        dst[(size_t)(ty + i) * VSTR + tx] = t[tx][ty + i];
}

// ---------------- bf16 GEMM, 128x64 tile (occupancy-tuned m97 staging) ----------------
template<int OUT_BF16, int QSCALE>
__global__ __launch_bounds__(256) void gemm_bf16(
    const __bf16* __restrict__ A, const __bf16* __restrict__ Bt,
    const float* __restrict__ bias, void* __restrict__ Cout,
    int M, int N, int K, int nx)
{
    __shared__ __bf16 Als[128 * 32];   // row*32 + k (64B rows)
    __shared__ __bf16 Bls[64 * 32];
    const int tid  = threadIdx.x;
    const int lane = tid & 63;
    const int wave = tid >> 6;
    const int lo = lane & 15, hi = lane >> 4;

    const int lin = blockIdx.x;
    const int cpx = gridDim.x >> 3;                    // grid % 8 == 0
    const int swz = (lin & 7) * cpx + (lin >> 3);      // XCD-contiguous
    const int bm = (swz / nx) * 128, bn = (swz % nx) * 64;
    const int wr = (wave >> 1) * 64, wc = (wave & 1) * 32;

    const __bf16* gA = A  + (size_t)(bm + wave * 16 + (lane >> 2)) * K + (lane & 3) * 8;
    const __bf16* gB = Bt + (size_t)(bn + wave * 16 + (lane >> 2)) * K + (lane & 3) * 8;
    __bf16* lA = &Als[wave * 16 * 32];
    __bf16* lB = &Bls[wave * 16 * 32];

    f32x4 acc[4][2] = {};

    for (int k0 = 0; k0 < K; k0 += 32) {
        __syncthreads();
        GLL16(gA + k0,                  lA);
        GLL16(gA + k0 + (size_t)64 * K, lA + 2048);
        GLL16(gB + k0,                  lB);
        __syncthreads();

        bf16x8 af[4], bfr[2];
#pragma unroll
        for (int i = 0; i < 4; i++)
            af[i] = *reinterpret_cast<const bf16x8*>(&Als[(wr + i * 16 + lo) * 32 + hi * 8]);
#pragma unroll
        for (int j = 0; j < 2; j++)
            bfr[j] = *reinterpret_cast<const bf16x8*>(&Bls[(wc + j * 16 + lo) * 32 + hi * 8]);
#pragma unroll
        for (int i = 0; i < 4; i++)
#pragma unroll
            for (int j = 0; j < 2; j++)
                acc[i][j] = __builtin_amdgcn_mfma_f32_16x16x32_bf16(af[i], bfr[j], acc[i][j], 0, 0, 0);
    }

#pragma unroll
    for (int j = 0; j < 2; j++) {
        int col = bn + wc + j * 16 + lo;
        float bv = bias[col];
#pragma unroll
        for (int i = 0; i < 4; i++) {
            int row0 = bm + wr + i * 16 + hi * 4;
#pragma unroll
            for (int rr = 0; rr < 4; rr++) {
                float v = acc[i][j][rr] + bv;
                if (QSCALE && col < DIMD) v *= CSC;
                if (OUT_BF16) ((__bf16*)Cout)[(size_t)(row0 + rr) * N + col] = (__bf16)v;
                else          ((float* )Cout)[(size_t)(row0 + rr) * N + col] = v;
            }
        }
    }
}

// ---------------- causal GQA flash attention (2 heads fused per wave) ----------------
// 512 blocks x 512 threads = 8 waves = 2 head-pairs x 2 tiles x 2 key-parities.
// z=bid&7 (XCD pin); co-resident blocks carry complementary work. Each wave
// computes TWO heads of the kv-group against the SAME K/V fragments: K b128 and
// V b64 LDS reads amortized 2x (GQA sharing), and the two heads give 2x ILP in
// the exp2->cvt->MFMA chain. 256-key super-chunks double-buffered in LDS
// (XOR-pre-swizzled source). Swapped QK^T; PV via 16x16x16 mfma, P in-register.
// Fixed-max exp2 softmax; parity partials combined through dead K/V LDS.
__global__ __launch_bounds__(512, 4) void attn_fwd(
    const __bf16* __restrict__ qkv, const __bf16* __restrict__ vt, __bf16* __restrict__ y)
{
    __shared__ __bf16 Ka[2][8192];        // [buf][key 128][d 64] swizzled 16B units
    __shared__ __bf16 Va[2][8192];        // [buf][d 64][key 128] swizzled 16B units
    const int tid  = threadIdx.x;
    const int wave = tid >> 6, lane = tid & 63;
    const int lo = lane & 15, hi = lane >> 4;
    const int hp = wave & 1, tt = (wave >> 1) & 1, par = wave >> 2;

    const int bid = blockIdx.x;
    const int z  = bid & 7;                      // b*4 + kh  -> XCD-pinned
    const int b  = z >> 2, kh = z & 3;
    const int c2 = bid >> 3;                     // 0..63
    const int p  = (c2 < 32) ? c2 : 95 - c2;     // co-resident blocks complement
    const int h0 = kh * 4 + hp * 2;              // this wave's two heads: h0, h0+1

    const int T  = tt ? 127 - p : p;
    const int qw = T * 16;
    const int cT = (T >> 2) + 1;                 // 64-key chunks for this tile
    const int cMax = ((127 - p) >> 2) + 1;
    const int S = (cMax + 1) >> 1;               // 256-key super-chunks staged

    const __bf16* base = qkv + (size_t)b * SEQ * QKVN;
    const __bf16* qp = base + h0 * HD;
    const __bf16* kp = base + DIMD + kh * HD;
    const __bf16* vp = vt + (size_t)z * HD * VSTR;   // [64][VSTR]

    // ---- staging sources (XOR-pre-swizzled; LDS dest linear, 4 GLL each) ----
    const int krow = lane >> 3;                         // 0..7
    const __bf16* kst = kp + (size_t)(wave * 16 + krow) * QKVN + ((lane & 7) ^ krow) * 8;
    const int vrow = lane >> 4;                         // 0..3
    const __bf16* vst0 = vp + (size_t)(wave * 8 + vrow) * VSTR + (((lane & 15) ^ vrow) * 8);
    const __bf16* vst1 = vp + (size_t)(wave * 8 + 4 + vrow) * VSTR + (((lane & 15) ^ (vrow + 4)) * 8);
    __bf16* kd = &Ka[0][wave * 1024];
    __bf16* vd = &Va[0][wave * 1024];

#define STAGE(s, buf)                                                       \
    do {                                                                    \
        const size_t ko = (size_t)(s) * 128 * QKVN;                         \
        const int    vo = (s) * 128;                                        \
        GLL16(kst + ko,                     kd + (buf) * 8192);             \
        GLL16(kst + ko + (size_t)8 * QKVN,  kd + (buf) * 8192 + 512);       \
        GLL16(vst0 + vo,                    vd + (buf) * 8192);             \
        GLL16(vst1 + vo,                    vd + (buf) * 8192 + 512);       \
    } while (0)

    const int xk = lo & 7;
    const int u0 = (hi ^ xk) * 8;          // K d-units hi
    const int u1 = ((hi + 4) ^ xk) * 8;    // K d-units hi+4
    int voff[4];
#pragma unroll
    for (int ks = 0; ks < 4; ks++)
        voff[ks] = (((par * 8 + ks * 2 + (hi >> 1)) ^ xk) << 3) + (hi & 1) * 4;

    // Q B-frags for both heads (pre-scaled by CSC in GEMM1)
    const __bf16* qrow = qp + (size_t)(qw + lo) * QKVN + hi * 8;
    bf16x8 bQ0a = *reinterpret_cast<const bf16x8*>(qrow);
    bf16x8 bQ1a = *reinterpret_cast<const bf16x8*>(qrow + 32);
    bf16x8 bQ0b = *reinterpret_cast<const bf16x8*>(qrow + HD);
    bf16x8 bQ1b = *reinterpret_cast<const bf16x8*>(qrow + HD + 32);

    f32x4 accA[4] = {}, accB[4] = {};      // head0 / head1 accumulators
    f32x4 ssva = {0.f, 0.f, 0.f, 0.f}, ssvb = {0.f, 0.f, 0.f, 0.f};

    STAGE(0, 0);
    __syncthreads();

    int cur = 0;
    for (int s = 0; s < S; ++s) {
        if (s + 1 < S) STAGE(s + 1, cur ^ 1);   // in flight across the compute

        const int ce = 2 * s + par;             // this wave's 64-key chunk index
        if (ce < cT) {
            const int kbase = ce * 64;
            const bool dT = (ce == cT - 1);
            const __bf16* Kb = &Ka[cur][par * 4096];
            const __bf16* Vb = &Va[cur][0];

#pragma unroll
            for (int ks = 0; ks < 4; ks++) {
                const __bf16* Kr = Kb + (ks * 16 + lo) * 64;
                bf16x8 aK0 = *reinterpret_cast<const bf16x8*>(Kr + u0);
                bf16x8 aK1 = *reinterpret_cast<const bf16x8*>(Kr + u1);

                f32x4 sa = {0.f, 0.f, 0.f, 0.f}, sb = {0.f, 0.f, 0.f, 0.f};
                sa = __builtin_amdgcn_mfma_f32_16x16x32_bf16(aK0, bQ0a, sa, 0, 0, 0);
                sb = __builtin_amdgcn_mfma_f32_16x16x32_bf16(aK0, bQ0b, sb, 0, 0, 0);
                sa = __builtin_amdgcn_mfma_f32_16x16x32_bf16(aK1, bQ1a, sa, 0, 0, 0);
                sb = __builtin_amdgcn_mfma_f32_16x16x32_bf16(aK1, bQ1b, sb, 0, 0, 0);

                bf16x4 pka, pkb;
#pragma unroll
                for (int r = 0; r < 4; r++) {
                    float ea = exp2f(sa[r]);
                    float eb = exp2f(sb[r]);
                    if (dT && (kbase + ks * 16 + hi * 4 + r > qw + lo)) { ea = 0.0f; eb = 0.0f; }
                    ssva[r] += ea;  ssvb[r] += eb;
                    pka[r] = (__bf16)ea;  pkb[r] = (__bf16)eb;
                }

                // PV: V frag read ONCE, used by both heads' pk
#pragma unroll
                for (int f = 0; f < 4; f++) {
                    bf16x4 vf = *reinterpret_cast<const bf16x4*>(&Vb[(f * 16 + lo) * 128] + voff[ks]);
                    s16x4 vfi = __builtin_bit_cast(s16x4, vf);
                    accA[f] = __builtin_amdgcn_mfma_f32_16x16x16bf16_1k(
                        vfi, __builtin_bit_cast(s16x4, pka), accA[f], 0, 0, 0);
                    accB[f] = __builtin_amdgcn_mfma_f32_16x16x16bf16_1k(
                        vfi, __builtin_bit_cast(s16x4, pkb), accB[f], 0, 0, 0);
                }
            }
        }

        __syncthreads();   // readers done with buf(cur); STAGE(s+1) drained
        cur ^= 1;
    }
#undef STAGE

    float ssa = (ssva[0] + ssva[1]) + (ssva[2] + ssva[3]);
    float ssb = (ssvb[0] + ssvb[1]) + (ssvb[2] + ssvb[3]);

    // ---- parity combine: single barrier, buffer overlaid on dead K/V LDS ----
    float* comb = (float*)&Ka[0][0];             // 4 slots x 64 lanes x 160B = 40KB
    const int sidx = ((wave & 3) * 64 + lane) * 40;
    if (par == 1) {
#pragma unroll
        for (int f = 0; f < 4; f++) {
            *reinterpret_cast<f32x4*>(&comb[sidx + f * 4])      = accA[f];
            *reinterpret_cast<f32x4*>(&comb[sidx + 16 + f * 4]) = accB[f];
        }
        comb[sidx + 32] = ssa;
        comb[sidx + 33] = ssb;
    }
    __syncthreads();
    if (par == 0) {
#pragma unroll
        for (int f = 0; f < 4; f++) {
            accA[f] += *reinterpret_cast<const f32x4*>(&comb[sidx + f * 4]);
            accB[f] += *reinterpret_cast<const f32x4*>(&comb[sidx + 16 + f * 4]);
        }
        ssa += comb[sidx + 32];
        ssb += comb[sidx + 33];

        // acc: q = lo (lane-local), d = f*16 + hi*4 + r
        ssa += __shfl_xor(ssa, 16);  ssa += __shfl_xor(ssa, 32);
        ssb += __shfl_xor(ssb, 16);  ssb += __shfl_xor(ssb, 32);
        float inva = 1.0f / ssa, invb = 1.0f / ssb;
        const size_t yb = (size_t)(b * SEQ + qw + lo) * DIMD + h0 * HD + hi * 4;
#pragma unroll
        for (int f = 0; f < 4; f++) {
            bf16x4 oa, ob;
#pragma unroll
            for (int r = 0; r < 4; r++) {
                oa[r] = (__bf16)(accA[f][r] * inva);
                ob[r] = (__bf16)(accB[f][r] * invb);
            }
            *reinterpret_cast<bf16x4*>(&y[yb + f * 16])      = oa;
            *reinterpret_cast<bf16x4*>(&y[yb + HD + f * 16]) = ob;
        }
    }
}

// ---------------- launcher ----------------
extern "C" void kernel_launch(void* const* d_in, const int* in_sizes, int n_in,
                              void* d_out, int out_size, void* d_ws, size_t ws_size,
                              hipStream_t stream) {
    const float* x    = (const float*)d_in[0];
    const float* Wqkv = (const float*)d_in[1];
    const float* bqkv = (const float*)d_in[2];
    const float* Wout = (const float*)d_in[3];
    const float* bout = (const float*)d_in[4];
    float* out = (float*)d_out;

    char* ws = (char*)d_ws;
    __bf16* xb    = (__bf16*)(ws);                          // 8 MB  (x bf16; later reused as y)
    __bf16* wqkvT = (__bf16*)(ws + ((size_t)8  << 20));     // 3 MB  [1536][1024] (dead after GEMM1)
    __bf16* woutT = (__bf16*)(ws + ((size_t)11 << 20));     // 2 MB  [1024][1024]
    __bf16* qkvb  = (__bf16*)(ws + ((size_t)13 << 20));     // 12 MB [4096][1536]
    __bf16* vtg   = wqkvT;                                  // alias: 2.2 MB Vt[8][64][VSTR]
    __bf16* yb    = xb;                                     // alias: xb dead after GEMM1

    const int M = NB * SEQ;   // 4096

    cvt_f32_bf16<<<(M * DIMD / 4 + 255) / 256, 256, 0, stream>>>(x, xb, M * DIMD / 4);
    transpose_cvt<<<dim3(QKVN / 32, DIMD / 32), dim3(32, 8), 0, stream>>>(Wqkv, wqkvT, DIMD, QKVN);
    transpose_cvt<<<dim3(DIMD / 32, DIMD / 32), dim3(32, 8), 0, stream>>>(Wout, woutT, DIMD, DIMD);

    // 128x64 tiles: 768 blocks (3/CU), XCD-swizzled
    gemm_bf16<1, 1><<<(M / 128) * (QKVN / 64), 256, 0, stream>>>(
        xb, wqkvT, bqkv, qkvb, M, QKVN, DIMD, QKVN / 64);

    transpose_v<<<dim3(SEQ / 32, HD / 32, NB * 4), dim3(32, 8), 0, stream>>>(qkvb, vtg);

    attn_fwd<<<512, 512, 0, stream>>>(qkvb, vtg, yb);

    // 128x64 tiles: 512 blocks (2/CU), XCD-swizzled
    gemm_bf16<0, 0><<<(M / 128) * (DIMD / 64), 256, 0, stream>>>(
        yb, woutT, bout, out, M, DIMD, DIMD, DIMD / 64);
}

// Round 14
// 103.990 us; speedup vs baseline: 1.1507x; 1.1507x over previous
//
#include <hip/hip_runtime.h>
#include <cstdint>
#include <cstddef>

// ---------------- types ----------------
typedef __bf16 bf16x8 __attribute__((ext_vector_type(8)));
typedef __bf16 bf16x4 __attribute__((ext_vector_type(4)));
typedef float  f32x4  __attribute__((ext_vector_type(4)));

#define DIMD 1024
#define SEQ  2048
#define NB   2
#define NH   16
#define HD   64
#define QKVN 1536   // 1024 + 2*256
#define VOFF 1280   // DIMD + 256
#define VSTR 2080   // padded V^T row stride (4160B: breaks L2 channel aliasing)
#define CSC  0.18033688011112042f   // 0.125 * log2(e), folded into q in GEMM1

// async global->LDS (16B per lane, wave-uniform LDS base)
typedef __attribute__((address_space(1))) const void* as1_cvp;
typedef __attribute__((address_space(3))) void* as3_vp;
#define GLL16(g, l) __builtin_amdgcn_global_load_lds((as1_cvp)(const void*)(g), (as3_vp)(void*)(l), 16, 0, 0)

// ---------------- fused prep: x->bf16 cvt + Wqkv^T + Wout^T (one launch) ----------------
// blocks [0,4096): cvt (256 float4 each); [4096,5632): Wqkv 32x32 transpose tiles;
// [5632,6656): Wout transpose tiles. Branch is block-uniform.
__global__ __launch_bounds__(256) void prep(
    const float* __restrict__ x, __bf16* __restrict__ xb,
    const float* __restrict__ Wqkv, __bf16* __restrict__ wqkvT,
    const float* __restrict__ Wout, __bf16* __restrict__ woutT)
{
    __shared__ float t[32][33];
    const int bidx = blockIdx.x;
    const int tid  = threadIdx.x;

    if (bidx < 4096) {                       // cvt: 4096*256 = 1M float4 = 4M elems
        int i = bidx * 256 + tid;
        float4 v = reinterpret_cast<const float4*>(x)[i];
        bf16x4 o;
        o[0] = (__bf16)v.x; o[1] = (__bf16)v.y; o[2] = (__bf16)v.z; o[3] = (__bf16)v.w;
        reinterpret_cast<bf16x4*>(xb)[i] = o;
        return;
    }

    const float* in; __bf16* out; int C, bx, by;
    if (bidx < 5632) {
        int idx = bidx - 4096;
        in = Wqkv; out = wqkvT; C = QKVN;
        bx = idx % 48; by = idx / 48;        // 48 x 32 tiles
    } else {
        int idx = bidx - 5632;
        in = Wout; out = woutT; C = DIMD;
        bx = idx & 31; by = idx >> 5;        // 32 x 32 tiles
    }
    const int tx = tid & 31, ty = tid >> 5;  // (32, 8)
#pragma unroll
    for (int i = 0; i < 32; i += 8)
        t[ty + i][tx] = in[(size_t)(by * 32 + ty + i) * C + bx * 32 + tx];
    __syncthreads();
#pragma unroll
    for (int i = 0; i < 32; i += 8)
        out[(size_t)(bx * 32 + ty + i) * DIMD + by * 32 + tx] = (__bf16)t[tx][ty + i];
}

// ---------------- bf16 [S][64] V-slice of qkv -> bf16 Vt[z][64][VSTR] ----------------
__global__ void transpose_v(const __bf16* __restrict__ qkv, __bf16* __restrict__ vtg) {
    __shared__ __bf16 t[32][34];
    const int z = blockIdx.z;           // b*4 + kh
    const int b = z >> 2, kh = z & 3;
    const int s0 = blockIdx.x * 32, d0 = blockIdx.y * 32;
    const int tx = threadIdx.x, ty = threadIdx.y;   // (32, 8)
    const __bf16* src = qkv + (size_t)b * SEQ * QKVN + VOFF + kh * HD;
#pragma unroll
    for (int i = 0; i < 32; i += 8)
        t[ty + i][tx] = src[(size_t)(s0 + ty + i) * QKVN + d0 + tx];
    __syncthreads();
    __bf16* dst = vtg + ((size_t)z * HD + d0) * VSTR + s0;
#pragma unroll
    for (int i = 0; i < 32; i += 8)
        dst[(size_t)(ty + i) * VSTR + tx] = t[tx][ty + i];
}

// ---------------- bf16 GEMM, 128x64 tile (occupancy-tuned m97 staging) ----------------
// 1D grid, bijective XCD swizzle; 4 waves (2Mx2N), wave = 64x32 (4x2 frags).
template<int OUT_BF16, int QSCALE>
__global__ __launch_bounds__(256) void gemm_bf16(
    const __bf16* __restrict__ A, const __bf16* __restrict__ Bt,
    const float* __restrict__ bias, void* __restrict__ Cout,
    int M, int N, int K, int nx)
{
    __shared__ __bf16 Als[128 * 32];   // row*32 + k (64B rows)
    __shared__ __bf16 Bls[64 * 32];
    const int tid  = threadIdx.x;
    const int lane = tid & 63;
    const int wave = tid >> 6;
    const int lo = lane & 15, hi = lane >> 4;

    const int lin = blockIdx.x;
    const int cpx = gridDim.x >> 3;                    // grid % 8 == 0
    const int swz = (lin & 7) * cpx + (lin >> 3);      // XCD-contiguous
    const int bm = (swz / nx) * 128, bn = (swz % nx) * 64;
    const int wr = (wave >> 1) * 64, wc = (wave & 1) * 32;

    const __bf16* gA = A  + (size_t)(bm + wave * 16 + (lane >> 2)) * K + (lane & 3) * 8;
    const __bf16* gB = Bt + (size_t)(bn + wave * 16 + (lane >> 2)) * K + (lane & 3) * 8;
    __bf16* lA = &Als[wave * 16 * 32];
    __bf16* lB = &Bls[wave * 16 * 32];

    f32x4 acc[4][2] = {};

    for (int k0 = 0; k0 < K; k0 += 32) {
        __syncthreads();
        GLL16(gA + k0,                  lA);
        GLL16(gA + k0 + (size_t)64 * K, lA + 2048);
        GLL16(gB + k0,                  lB);
        __syncthreads();

        bf16x8 af[4], bfr[2];
#pragma unroll
        for (int i = 0; i < 4; i++)
            af[i] = *reinterpret_cast<const bf16x8*>(&Als[(wr + i * 16 + lo) * 32 + hi * 8]);
#pragma unroll
        for (int j = 0; j < 2; j++)
            bfr[j] = *reinterpret_cast<const bf16x8*>(&Bls[(wc + j * 16 + lo) * 32 + hi * 8]);
#pragma unroll
        for (int i = 0; i < 4; i++)
#pragma unroll
            for (int j = 0; j < 2; j++)
                acc[i][j] = __builtin_amdgcn_mfma_f32_16x16x32_bf16(af[i], bfr[j], acc[i][j], 0, 0, 0);
    }

#pragma unroll
    for (int j = 0; j < 2; j++) {
        int col = bn + wc + j * 16 + lo;
        float bv = bias[col];
#pragma unroll
        for (int i = 0; i < 4; i++) {
            int row0 = bm + wr + i * 16 + hi * 4;
#pragma unroll
            for (int rr = 0; rr < 4; rr++) {
                float v = acc[i][j][rr] + bv;
                if (QSCALE && col < DIMD) v *= CSC;
                if (OUT_BF16) ((__bf16*)Cout)[(size_t)(row0 + rr) * N + col] = (__bf16)v;
                else          ((float* )Cout)[(size_t)(row0 + rr) * N + col] = v;
            }
        }
    }
}

// ---------------- causal GQA flash attention (in-block split-K, 8 waves) ----------------
// r10 structure (best measured: 46.7us). 512 blocks x 512 threads = 8 waves =
// 4 heads x 2 key-parities. bid&7 = b*4+kh (XCD pin). Each wave handles tiles
// A=p, B=127-p (16 q-rows each) over its parity's 64-key chunks. 128-key
// super-chunks staged once per block (K[128][64], Vt[64][128], XOR-swizzled
// source, single-buffered). Fixed-max exp2 softmax -> split-K is a pure sum.
__global__ __launch_bounds__(512, 4) void attn_fwd(
    const __bf16* __restrict__ qkv, const __bf16* __restrict__ vt, __bf16* __restrict__ y)
{
    __shared__ __bf16 Kls[128 * 64];        // [key][d], row-XOR-swizzled 16B units
    __shared__ __bf16 Vls[64 * 128];        // [d][key], row-XOR-swizzled 16B units
    __shared__ __bf16 Pls[8][2][16][72];    // [wave][tile][q][k], 144B rows
    const int tid  = threadIdx.x;
    const int wave = tid >> 6, lane = tid & 63;
    const int lo = lane & 15, hi = lane >> 4;
    const int head = wave & 3, par = wave >> 2;

    const int bid = blockIdx.x;
    const int z  = bid & 7;              // b*4 + kh  -> XCD-pinned
    const int b  = z >> 2, kh = z & 3;
    const int p  = bid >> 3;             // 0..63
    const int h  = kh * 4 + head;

    const int TA = p, TB = 127 - p;
    const int qwA = TA * 16, qwB = TB * 16;
    const int cA = (TA >> 2) + 1, cB = (TB >> 2) + 1;   // 64-key chunk counts
    const int nsc = (cB + 1) >> 1;                      // 128-key super-chunks

    const __bf16* base = qkv + (size_t)b * SEQ * QKVN;
    const __bf16* qp = base + h * HD;
    const __bf16* kp = base + DIMD + kh * HD;
    const __bf16* vp = vt + (size_t)z * HD * VSTR;      // [64][VSTR]

    // ---- staging sources (XOR-pre-swizzled; LDS dest linear) ----
    const int srow = lane >> 3;                       // 0..7
    const int sun  = ((lane & 7) ^ srow) * 8;
    const __bf16* kst0 = kp + (size_t)(wave * 16 + srow) * QKVN + sun;
    const __bf16* kst1 = kp + (size_t)(wave * 16 + 8 + srow) * QKVN + sun;
    const int vrow = lane >> 4;                       // 0..3
    const int vun0 = ((lane & 15) ^ vrow) * 8;
    const int vun1 = ((lane & 15) ^ (vrow + 4)) * 8;
    const __bf16* vst0 = vp + (size_t)(wave * 8 + vrow) * VSTR + vun0;
    const __bf16* vst1 = vp + (size_t)(wave * 8 + 4 + vrow) * VSTR + vun1;
    __bf16* kdst = &Kls[wave * 1024];
    __bf16* vdst = &Vls[wave * 1024];

#define STAGE(s)                                            \
    do {                                                    \
        const size_t ko = (size_t)(s) * 128 * QKVN;         \
        const int    vo = (s) * 128;                        \
        GLL16(kst0 + ko, kdst);                             \
        GLL16(kst1 + ko, kdst + 512);                       \
        GLL16(vst0 + vo, vdst);                             \
        GLL16(vst1 + vo, vdst + 512);                       \
    } while (0)

    // ---- swizzled fragment-read offsets ----
    const int xk = lo & 7;
    const int u0 = (hi ^ xk) * 8;          // K d-units hi
    const int u1 = ((hi + 4) ^ xk) * 8;    // K d-units hi+4
    const int kb = par * 64;               // this parity's key base within tile

    // Q B-frags (pre-scaled by CSC in GEMM1): lane holds Q[qw+lo][hi*8..+8]
    bf16x8 bQA0 = *reinterpret_cast<const bf16x8*>(qp + (size_t)(qwA + lo) * QKVN + hi * 8);
    bf16x8 bQA1 = *reinterpret_cast<const bf16x8*>(qp + (size_t)(qwA + lo) * QKVN + 32 + hi * 8);
    bf16x8 bQB0 = *reinterpret_cast<const bf16x8*>(qp + (size_t)(qwB + lo) * QKVN + hi * 8);
    bf16x8 bQB1 = *reinterpret_cast<const bf16x8*>(qp + (size_t)(qwB + lo) * QKVN + 32 + hi * 8);

    f32x4 accA[4] = {}, accB[4] = {};
    float ssA = 0.0f, ssB = 0.0f;

    STAGE(0);
    __syncthreads();

    for (int s = 0; s < nsc; ++s) {
        const int ce = 2 * s + par;        // this wave's 64-key chunk index
        const int kt = ce << 6;            // global key base (mask arithmetic)
        const bool aB = (ce < cB), dB = (ce == cB - 1);
        const bool aA = (ce < cA), dA = (ce == cA - 1);

        if (aB) {
            // S^T = K Q^T per 16-key subtile; lane gets q=lo, k = kt+16ks+hi*4+r
#pragma unroll
            for (int ks = 0; ks < 4; ks++) {
                const __bf16* Kr = &Kls[(kb + ks * 16 + lo) * 64];
                bf16x8 aK0 = *reinterpret_cast<const bf16x8*>(Kr + u0);
                bf16x8 aK1 = *reinterpret_cast<const bf16x8*>(Kr + u1);

                {   // tile B
                    f32x4 sv = {0.f, 0.f, 0.f, 0.f};
                    sv = __builtin_amdgcn_mfma_f32_16x16x32_bf16(aK0, bQB0, sv, 0, 0, 0);
                    sv = __builtin_amdgcn_mfma_f32_16x16x32_bf16(aK1, bQB1, sv, 0, 0, 0);
                    bf16x4 pk;
#pragma unroll
                    for (int r = 0; r < 4; r++) {
                        float e = exp2f(sv[r]);
                        if (dB && (kt + ks * 16 + hi * 4 + r > qwB + lo)) e = 0.0f;
                        ssB += e;
                        pk[r] = (__bf16)e;
                    }
                    *reinterpret_cast<bf16x4*>(&Pls[wave][1][lo][ks * 16 + hi * 4]) = pk;
                }
                if (aA) {   // tile A — reuses aK0/aK1
                    f32x4 sv = {0.f, 0.f, 0.f, 0.f};
                    sv = __builtin_amdgcn_mfma_f32_16x16x32_bf16(aK0, bQA0, sv, 0, 0, 0);
                    sv = __builtin_amdgcn_mfma_f32_16x16x32_bf16(aK1, bQA1, sv, 0, 0, 0);
                    bf16x4 pk;
#pragma unroll
                    for (int r = 0; r < 4; r++) {
                        float e = exp2f(sv[r]);
                        if (dA && (kt + ks * 16 + hi * 4 + r > qwA + lo)) e = 0.0f;
                        ssA += e;
                        pk[r] = (__bf16)e;
                    }
                    *reinterpret_cast<bf16x4*>(&Pls[wave][0][lo][ks * 16 + hi * 4]) = pk;
                }
            }

            // P x V : V frags shared by both tiles
#pragma unroll
            for (int k2 = 0; k2 < 2; k2++) {
                const int uv = ((8 * par + k2 * 4 + hi) ^ xk) * 8;
                bf16x8 v0 = *reinterpret_cast<const bf16x8*>(&Vls[(0 * 16 + lo) * 128] + uv);
                bf16x8 v1 = *reinterpret_cast<const bf16x8*>(&Vls[(1 * 16 + lo) * 128] + uv);
                bf16x8 v2 = *reinterpret_cast<const bf16x8*>(&Vls[(2 * 16 + lo) * 128] + uv);
                bf16x8 v3 = *reinterpret_cast<const bf16x8*>(&Vls[(3 * 16 + lo) * 128] + uv);
                bf16x8 pB = *reinterpret_cast<const bf16x8*>(&Pls[wave][1][lo][k2 * 32 + hi * 8]);
                accB[0] = __builtin_amdgcn_mfma_f32_16x16x32_bf16(pB, v0, accB[0], 0, 0, 0);
                accB[1] = __builtin_amdgcn_mfma_f32_16x16x32_bf16(pB, v1, accB[1], 0, 0, 0);
                accB[2] = __builtin_amdgcn_mfma_f32_16x16x32_bf16(pB, v2, accB[2], 0, 0, 0);
                accB[3] = __builtin_amdgcn_mfma_f32_16x16x32_bf16(pB, v3, accB[3], 0, 0, 0);
                if (aA) {
                    bf16x8 pA = *reinterpret_cast<const bf16x8*>(&Pls[wave][0][lo][k2 * 32 + hi * 8]);
                    accA[0] = __builtin_amdgcn_mfma_f32_16x16x32_bf16(pA, v0, accA[0], 0, 0, 0);
                    accA[1] = __builtin_amdgcn_mfma_f32_16x16x32_bf16(pA, v1, accA[1], 0, 0, 0);
                    accA[2] = __builtin_amdgcn_mfma_f32_16x16x32_bf16(pA, v2, accA[2], 0, 0, 0);
                    accA[3] = __builtin_amdgcn_mfma_f32_16x16x32_bf16(pA, v3, accA[3], 0, 0, 0);
                }
            }
        }

        __syncthreads();                       // all reads of this super-chunk done
        if (s + 1 < nsc) {
            STAGE(s + 1);
            __syncthreads();                   // staged data visible
        }
    }
#undef STAGE

    // ---- parity combine (pure sum: fixed-max softmax) through LDS (overlays Pls) ----
    float* cls = (float*)&Pls[0][0][0][0];
    const int cbase = (head * 64 + lane) * 36;   // 144B stride, 16B-aligned
    if (par == 1) {
#pragma unroll
        for (int f = 0; f < 4; f++) {
            *reinterpret_cast<f32x4*>(&cls[cbase + f * 4])      = accA[f];
            *reinterpret_cast<f32x4*>(&cls[cbase + 16 + f * 4]) = accB[f];
        }
        cls[cbase + 32] = ssA;
        cls[cbase + 33] = ssB;
    }
    __syncthreads();
    if (par == 0) {
#pragma unroll
        for (int f = 0; f < 4; f++) {
            accA[f] += *reinterpret_cast<f32x4*>(&cls[cbase + f * 4]);
            accB[f] += *reinterpret_cast<f32x4*>(&cls[cbase + 16 + f * 4]);
        }
        ssA += cls[cbase + 32];
        ssB += cls[cbase + 33];

        ssA += __shfl_xor(ssA, 16);  ssA += __shfl_xor(ssA, 32);
        ssB += __shfl_xor(ssB, 16);  ssB += __shfl_xor(ssB, 32);
#pragma unroll
        for (int r = 0; r < 4; r++) {
            float srA = __shfl(ssA, hi * 4 + r);
            float srB = __shfl(ssB, hi * 4 + r);
            float invA = 1.0f / srA, invB = 1.0f / srB;
            int qA = qwA + hi * 4 + r, qB = qwB + hi * 4 + r;
#pragma unroll
            for (int f = 0; f < 4; f++) {
                y[(size_t)(b * SEQ + qA) * DIMD + h * HD + f * 16 + lo] = (__bf16)(accA[f][r] * invA);
                y[(size_t)(b * SEQ + qB) * DIMD + h * HD + f * 16 + lo] = (__bf16)(accB[f][r] * invB);
            }
        }
    }
}

// ---------------- launcher ----------------
extern "C" void kernel_launch(void* const* d_in, const int* in_sizes, int n_in,
                              void* d_out, int out_size, void* d_ws, size_t ws_size,
                              hipStream_t stream) {
    const float* x    = (const float*)d_in[0];
    const float* Wqkv = (const float*)d_in[1];
    const float* bqkv = (const float*)d_in[2];
    const float* Wout = (const float*)d_in[3];
    const float* bout = (const float*)d_in[4];
    float* out = (float*)d_out;

    char* ws = (char*)d_ws;
    __bf16* xb    = (__bf16*)(ws);                          // 8 MB  (x bf16; later reused as y)
    __bf16* wqkvT = (__bf16*)(ws + ((size_t)8  << 20));     // 3 MB  [1536][1024] (dead after GEMM1)
    __bf16* woutT = (__bf16*)(ws + ((size_t)11 << 20));     // 2 MB  [1024][1024]
    __bf16* qkvb  = (__bf16*)(ws + ((size_t)13 << 20));     // 12 MB [4096][1536]
    __bf16* vtg   = wqkvT;                                  // alias: 2.2 MB Vt[8][64][VSTR]
    __bf16* yb    = xb;                                     // alias: xb dead after GEMM1

    const int M = NB * SEQ;   // 4096

    prep<<<6656, 256, 0, stream>>>(x, xb, Wqkv, wqkvT, Wout, woutT);

    // 128x64 tiles: 768 blocks (3/CU), XCD-swizzled
    gemm_bf16<1, 1><<<(M / 128) * (QKVN / 64), 256, 0, stream>>>(
        xb, wqkvT, bqkv, qkvb, M, QKVN, DIMD, QKVN / 64);

    transpose_v<<<dim3(SEQ / 32, HD / 32, NB * 4), dim3(32, 8), 0, stream>>>(qkvb, vtg);

    attn_fwd<<<512, 512, 0, stream>>>(qkvb, vtg, yb);

    // 128x64 tiles: 512 blocks (2/CU), XCD-swizzled
    gemm_bf16<0, 0><<<(M / 128) * (DIMD / 64), 256, 0, stream>>>(
        yb, woutT, bout, out, M, DIMD, DIMD, DIMD / 64);
}